// Round 8
// baseline (73.411 us; speedup 1.0000x reference)
//
#include <hip/hip_runtime.h>

typedef __bf16 bf16_t;
typedef bf16_t bf16x8 __attribute__((ext_vector_type(8)));
typedef float f32x4 __attribute__((ext_vector_type(4)));

#define Bsz 4096   // batch rows (M)
#define Csz 4096   // centers (N)
#define Dsz 1024   // data dim (K)
#define BM 128
#define BN 128
#define BK 64
#define NT (Dsz/BK)         // 16 K-tiles
#define NPC 64              // partial column-groups: 32 bn-tiles x 2 wc

// RNE f32 -> bf16 bits
__device__ inline unsigned short f2bf(float f){
  unsigned u = __float_as_uint(f);
  u += 0x7FFFu + ((u >> 16) & 1u);
  return (unsigned short)(u >> 16);
}

// ---------------- prep: x2/c2 (f32 exact) + bf16 conversion ----------------
__global__ __launch_bounds__(256) void prep_kernel(
    const float* __restrict__ x, const float* __restrict__ cen,
    unsigned short* __restrict__ xb, unsigned short* __restrict__ cb,
    float* __restrict__ x2, float* __restrict__ c2)
{
  int w = blockIdx.x * 4 + (threadIdx.x >> 6);   // global wave id, one row each
  int lane = threadIdx.x & 63;
  const float* src; unsigned short* dst; float* sq; int row;
  if (w < Bsz) { row = w;       src = x;   dst = xb; sq = x2; }
  else         { row = w - Bsz; src = cen; dst = cb; sq = c2; }

  const float4* s4 = (const float4*)(src + (size_t)row * Dsz);
  unsigned short* d = dst + (size_t)row * Dsz;
  float ss = 0.f;
  #pragma unroll
  for (int t = 0; t < 4; ++t){
    float4 v = s4[t * 64 + lane];
    ss += v.x*v.x + v.y*v.y + v.z*v.z + v.w*v.w;
    ushort4 u; u.x = f2bf(v.x); u.y = f2bf(v.y); u.z = f2bf(v.z); u.w = f2bf(v.w);
    *(ushort4*)(d + (size_t)(t * 64 + lane) * 4) = u;
  }
  #pragma unroll
  for (int off = 32; off >= 1; off >>= 1) ss += __shfl_xor(ss, off, 64);
  if (lane == 0) sq[row] = ss;
}

// --------- m97-faithful 128x128 fused GEMM + RBF epilogue ---------
// 256 thr = 4 waves (2 wr x 2 wc). Per wave: 64x64 output = 4x4 frags 16x16.
// Single LDS buffer (A 128x64 + B 128x64 bf16 = 32 KiB) -> 4 blocks/CU.
// Per tile: stage via 8x global_load_lds(16B) -> __syncthreads() (compiler
// drains vmcnt) -> kk=0,1 plain C++ bf16x8 reads + 16 MFMA (compiler emits
// ds_read_b128 + fine lgkmcnt) -> __syncthreads(). No inline asm in the loop.
// Swizzle: LDS[r][c16] = G[r][c16 ^ (r&7)] -> 0 bank conflicts (measured).
// NEW (R8): K-loop start STAGGER. All blocks had identical periods and
// phase-locked stage/drain windows; since sum over k is commutative, each
// block starts at tile (id&3)*4 and wraps. A-panel sharers (same id&3 in the
// rect mapping) stay k-synced for L2 reuse; co-resident blocks de-phase, so
// another block computes while one drains at its barrier.
__global__ __launch_bounds__(256, 4) void rbf_gemm_kernel(
    const unsigned short* __restrict__ xb, const unsigned short* __restrict__ cb,
    const float* __restrict__ x2, const float* __restrict__ c2,
    const float* __restrict__ beta, const float* __restrict__ W,
    float* __restrict__ partials)
{
  __shared__ __align__(16) unsigned short As[BM * BK];  // 16 KiB
  __shared__ __align__(16) unsigned short Bs[BN * BK];  // 16 KiB

  const int tid  = threadIdx.x;
  const int wid  = tid >> 6;
  const int lane = tid & 63;
  const int wr   = wid >> 1;        // 0..1
  const int wc   = wid & 1;         // 0..1
  const int l15  = lane & 15;
  const int lhi  = lane >> 4;

  // XCD mapping: xcd = id%8; each XCD owns two 8x8 (bm,bn) rects -> ~4 MB
  // L2 working set per XCD. (R4: FETCH 37.5 -> 26 MB)
  const int id   = blockIdx.x;          // 0..1023
  const int xcd  = id & 7;
  const int jj   = id >> 3;             // 0..127
  const int rect = xcd + 8 * (jj >> 6); // 0..15
  const int pos  = jj & 63;             // 0..63
  const int bm   = (rect & 3) * 8 + (pos & 7);
  const int bn   = (rect >> 2) * 8 + (pos >> 3);

  const unsigned short* gA = xb + (size_t)(bm * BM) * Dsz;
  const unsigned short* gB = cb + (size_t)(bn * BN) * Dsz;

  // staging: one gload_lds = 64 lanes x 16B = 8 rows x 8 chunks; 256 thr
  // cover 32 rows/pass; 4 passes per 128-row panel; 8 gload/thread/tile.
  const int srow   = tid >> 3;                 // 0..31
  const int schunk = (tid & 7) ^ (srow & 7);   // pre-swizzled source chunk

  // K-loop start stagger (de-phase co-resident blocks' drain windows)
  const int koff = (id & 3) << 2;              // 0,4,8,12

  f32x4 acc[4][4];
  #pragma unroll
  for (int mi = 0; mi < 4; ++mi)
    #pragma unroll
    for (int ni = 0; ni < 4; ++ni)
      acc[mi][ni] = (f32x4){0.f, 0.f, 0.f, 0.f};

  for (int t = 0; t < NT; ++t){
    const int tp = (t + koff) & (NT - 1);      // physical K-tile index
    // ---- stage tile tp (linear LDS dest, pre-swizzled global source) ----
    #pragma unroll
    for (int r_ = 0; r_ < 4; ++r_){
      const unsigned short* ga_ = gA + (size_t)(r_*32 + srow) * Dsz + tp*BK + schunk*8;
      __builtin_amdgcn_global_load_lds(
        (const __attribute__((address_space(1))) unsigned int*)ga_,
        (__attribute__((address_space(3))) unsigned int*)&As[r_*2048 + wid*512], 16, 0, 0);
      const unsigned short* gb_ = gB + (size_t)(r_*32 + srow) * Dsz + tp*BK + schunk*8;
      __builtin_amdgcn_global_load_lds(
        (const __attribute__((address_space(1))) unsigned int*)gb_,
        (__attribute__((address_space(3))) unsigned int*)&Bs[r_*2048 + wid*512], 16, 0, 0);
    }
    __syncthreads();   // compiler drains vmcnt before barrier -> tile ready

    // ---- compute: plain C++ reads, compiler-scheduled waits ----
    #pragma unroll
    for (int kk = 0; kk < 2; ++kk){
      bf16x8 av[4], bv[4];
      const int chunk = ((kk*4 + lhi) ^ (l15 & 7)) * 8;
      #pragma unroll
      for (int mi = 0; mi < 4; ++mi)
        av[mi] = *(const bf16x8*)&As[(wr*64 + mi*16 + l15)*64 + chunk];
      #pragma unroll
      for (int ni = 0; ni < 4; ++ni)
        bv[ni] = *(const bf16x8*)&Bs[(wc*64 + ni*16 + l15)*64 + chunk];
      #pragma unroll
      for (int mi = 0; mi < 4; ++mi)
        #pragma unroll
        for (int ni = 0; ni < 4; ++ni)
          acc[mi][ni] = __builtin_amdgcn_mfma_f32_16x16x32_bf16(av[mi], bv[ni], acc[mi][ni], 0, 0, 0);
    }
    __syncthreads();   // protect LDS before next stage overwrites
  }

  // ---- fused epilogue: d2 -> dist -> exp -> *W, then column-sum ----
  const int rowbase0 = bm * BM + wr * 64;
  f32x4 rs[4];
  #pragma unroll
  for (int mi = 0; mi < 4; ++mi) rs[mi] = (f32x4){0.f, 0.f, 0.f, 0.f};

  f32x4 x2r[4];
  #pragma unroll
  for (int mi = 0; mi < 4; ++mi)
    x2r[mi] = *(const f32x4*)&x2[rowbase0 + mi * 16 + lhi * 4];

  #pragma unroll
  for (int ni = 0; ni < 4; ++ni){
    const int col = bn * BN + wc * 64 + ni * 16 + l15;
    const float c2v = c2[col], bt = beta[col], wv = W[col];
    #pragma unroll
    for (int mi = 0; mi < 4; ++mi)
      #pragma unroll
      for (int j = 0; j < 4; ++j){
        float s    = acc[mi][ni][j];
        float d2   = x2r[mi][j] + c2v - 2.0f * s;
        float dist = sqrtf(fmaxf(d2, 0.0f));
        rs[mi][j] += wv * __expf(-bt * dist);   // exp(<=0) can't be inf
      }
  }

  // reduce over the 16 lanes holding different cols; write per-(bn,wc) partials
  const size_t pcbase = (size_t)(bn * 2 + wc) * Bsz;
  #pragma unroll
  for (int mi = 0; mi < 4; ++mi){
    #pragma unroll
    for (int j = 0; j < 4; ++j){
      float v = rs[mi][j];
      v += __shfl_xor(v, 1, 16);
      v += __shfl_xor(v, 2, 16);
      v += __shfl_xor(v, 4, 16);
      v += __shfl_xor(v, 8, 16);
      rs[mi][j] = v;
    }
    if (l15 == 0)
      *(f32x4*)&partials[pcbase + rowbase0 + mi * 16 + lhi * 4] = rs[mi];
  }
}

// ---------------- final reduction over column-groups ----------------
__global__ __launch_bounds__(256) void reduce_kernel(
    const float* __restrict__ partials, const float* __restrict__ bias,
    float* __restrict__ out)
{
  int b = blockIdx.x * 256 + threadIdx.x;
  float s = bias[0];
  #pragma unroll
  for (int t = 0; t < NPC; ++t) s += partials[(size_t)t * Bsz + b];
  out[b] = s;
}

// ---------------- naive f32 fallback (only if ws too small) ----------------
__global__ __launch_bounds__(256) void rbf_naive_kernel(
    const float* __restrict__ x, const float* __restrict__ cen,
    const float* __restrict__ beta, const float* __restrict__ W,
    const float* __restrict__ bias, float* __restrict__ out)
{
  __shared__ float4 xs4[Dsz / 4];
  __shared__ float red[256];
  int b = blockIdx.x;
  for (int i = threadIdx.x; i < Dsz / 4; i += 256)
    xs4[i] = ((const float4*)(x + (size_t)b * Dsz))[i];
  __syncthreads();
  float acc = 0.f;
  for (int j = threadIdx.x; j < Csz; j += 256){
    const float4* c4 = (const float4*)(cen + (size_t)j * Dsz);
    float d2 = 0.f;
    for (int k = 0; k < Dsz / 4; ++k){
      float4 cv = c4[k], xv = xs4[k];
      float a0 = xv.x - cv.x, a1 = xv.y - cv.y, a2 = xv.z - cv.z, a3 = xv.w - cv.w;
      d2 += a0*a0 + a1*a1 + a2*a2 + a3*a3;
    }
    acc += W[j] * expf(-beta[j] * sqrtf(fmaxf(d2, 0.f)));
  }
  red[threadIdx.x] = acc;
  __syncthreads();
  for (int s = 128; s >= 1; s >>= 1){
    if (threadIdx.x < s) red[threadIdx.x] += red[threadIdx.x + s];
    __syncthreads();
  }
  if (threadIdx.x == 0) out[b] = red[0] + bias[0];
}

extern "C" void kernel_launch(void* const* d_in, const int* in_sizes, int n_in,
                              void* d_out, int out_size, void* d_ws, size_t ws_size,
                              hipStream_t stream)
{
  const float* x    = (const float*)d_in[0];
  const float* cen  = (const float*)d_in[1];
  const float* beta = (const float*)d_in[2];
  const float* W    = (const float*)d_in[3];
  const float* bias = (const float*)d_in[4];
  float* out = (float*)d_out;

  const size_t off_xb = 0;
  const size_t off_cb = off_xb + (size_t)Bsz * Dsz * sizeof(unsigned short);
  const size_t off_x2 = off_cb + (size_t)Csz * Dsz * sizeof(unsigned short);
  const size_t off_c2 = off_x2 + (size_t)Bsz * sizeof(float);
  const size_t off_p  = off_c2 + (size_t)Csz * sizeof(float);
  const size_t need   = off_p  + (size_t)NPC * Bsz * sizeof(float);

  if (ws_size < need){
    rbf_naive_kernel<<<Bsz, 256, 0, stream>>>(x, cen, beta, W, bias, out);
    return;
  }

  char* ws = (char*)d_ws;
  unsigned short* xb = (unsigned short*)(ws + off_xb);
  unsigned short* cb = (unsigned short*)(ws + off_cb);
  float* x2 = (float*)(ws + off_x2);
  float* c2 = (float*)(ws + off_c2);
  float* pp = (float*)(ws + off_p);

  prep_kernel<<<(Bsz + Csz) / 4, 256, 0, stream>>>(x, cen, xb, cb, x2, c2);
  rbf_gemm_kernel<<<1024, 256, 0, stream>>>(xb, cb, x2, c2, beta, W, pp);
  reduce_kernel<<<Bsz / 256, 256, 0, stream>>>(pp, bias, out);
}

// Round 10
// 54.173 us; speedup vs baseline: 1.3551x; 1.3551x over previous
//
#include <hip/hip_runtime.h>

typedef __bf16 bf16_t;
typedef bf16_t bf16x8 __attribute__((ext_vector_type(8)));
typedef float f32x4 __attribute__((ext_vector_type(4)));

#define Bsz 4096   // batch rows (M)
#define Csz 4096   // centers (N)
#define Dsz 1024   // data dim (K)
#define BM 128
#define BN 128
#define BK 64
#define NT (Dsz/BK)         // 16 K-tiles

// RNE f32 -> bf16 bits
__device__ inline unsigned short f2bf(float f){
  unsigned u = __float_as_uint(f);
  u += 0x7FFFu + ((u >> 16) & 1u);
  return (unsigned short)(u >> 16);
}

// ---------------- prep: x2/c2 (f32 exact) + bf16 convert + out=bias --------
// 1024 blocks x 4 waves x 2 rows = 8192 rows. Also initializes out[row]=bias
// so the GEMM can finish with device-scope atomicAdd (stream order guarantees
// prep completes before the GEMM kernel starts).
__global__ __launch_bounds__(256) void prep_kernel(
    const float* __restrict__ x, const float* __restrict__ cen,
    const float* __restrict__ bias,
    unsigned short* __restrict__ xb, unsigned short* __restrict__ cb,
    float* __restrict__ x2, float* __restrict__ c2,
    float* __restrict__ out)
{
  const int wid  = threadIdx.x >> 6;
  const int lane = threadIdx.x & 63;
  #pragma unroll
  for (int rr = 0; rr < 2; ++rr){
    const int w = blockIdx.x * 8 + wid * 2 + rr;   // 0..8191
    const float* src; unsigned short* dst; float* sq; int row;
    if (w < Bsz) { row = w;       src = x;   dst = xb; sq = x2; }
    else         { row = w - Bsz; src = cen; dst = cb; sq = c2; }

    const float4* s4 = (const float4*)(src + (size_t)row * Dsz);
    unsigned short* d = dst + (size_t)row * Dsz;
    float ss = 0.f;
    #pragma unroll
    for (int t = 0; t < 4; ++t){
      float4 v = s4[t * 64 + lane];
      ss += v.x*v.x + v.y*v.y + v.z*v.z + v.w*v.w;
      ushort4 u; u.x = f2bf(v.x); u.y = f2bf(v.y); u.z = f2bf(v.z); u.w = f2bf(v.w);
      *(ushort4*)(d + (size_t)(t * 64 + lane) * 4) = u;
    }
    #pragma unroll
    for (int off = 32; off >= 1; off >>= 1) ss += __shfl_xor(ss, off, 64);
    if (lane == 0){
      sq[row] = ss;
      if (w < Bsz) out[row] = bias[0];   // re-init every call (atomic target)
    }
  }
}

// --------- R8-proven 128x128 GEMM + fused RBF epilogue, atomic finish ------
// 256 thr = 4 waves (2 wr x 2 wc). Per wave: 64x64 output = 4x4 frags 16x16.
// Single LDS buffer (A 128x64 + B 128x64 bf16 = 32 KiB) -> 4 blocks/CU.
// Per tile: stage via 8x global_load_lds(16B) -> __syncthreads() -> kk=0,1
// plain C++ bf16x8 reads + 16 MFMA (compiler-scheduled lgkmcnt) ->
// __syncthreads(). Swizzle: LDS[r][c16] = G[r][c16 ^ (r&7)] -> 0 conflicts.
// K-loop start stagger de-phases co-resident blocks' drain windows (R8: +3us).
// Epilogue: d2 -> dist -> exp -> *W -> 16-lane reduce -> atomicAdd(out[row])
// (device-scope, cross-XCD safe; replaces the separate reduce kernel).
__global__ __launch_bounds__(256, 4) void rbf_gemm_kernel(
    const unsigned short* __restrict__ xb, const unsigned short* __restrict__ cb,
    const float* __restrict__ x2, const float* __restrict__ c2,
    const float* __restrict__ beta, const float* __restrict__ W,
    float* __restrict__ out)
{
  __shared__ __align__(16) unsigned short As[BM * BK];  // 16 KiB
  __shared__ __align__(16) unsigned short Bs[BN * BK];  // 16 KiB

  const int tid  = threadIdx.x;
  const int wid  = tid >> 6;
  const int lane = tid & 63;
  const int wr   = wid >> 1;        // 0..1
  const int wc   = wid & 1;         // 0..1
  const int l15  = lane & 15;
  const int lhi  = lane >> 4;

  // XCD mapping: xcd = id%8; each XCD owns two 8x8 (bm,bn) rects -> ~4 MB
  // L2 working set per XCD. (R4: FETCH 37.5 -> 26 MB)
  const int id   = blockIdx.x;          // 0..1023
  const int xcd  = id & 7;
  const int jj   = id >> 3;             // 0..127
  const int rect = xcd + 8 * (jj >> 6); // 0..15
  const int pos  = jj & 63;             // 0..63
  const int bm   = (rect & 3) * 8 + (pos & 7);
  const int bn   = (rect >> 2) * 8 + (pos >> 3);

  const unsigned short* gA = xb + (size_t)(bm * BM) * Dsz;
  const unsigned short* gB = cb + (size_t)(bn * BN) * Dsz;

  // staging: one gload_lds = 64 lanes x 16B = 8 rows x 8 chunks; 256 thr
  // cover 32 rows/pass; 4 passes per 128-row panel; 8 gload/thread/tile.
  const int srow   = tid >> 3;                 // 0..31
  const int schunk = (tid & 7) ^ (srow & 7);   // pre-swizzled source chunk

  // K-loop start stagger (de-phase co-resident blocks' drain windows)
  const int koff = (id & 3) << 2;              // 0,4,8,12

  f32x4 acc[4][4];
  #pragma unroll
  for (int mi = 0; mi < 4; ++mi)
    #pragma unroll
    for (int ni = 0; ni < 4; ++ni)
      acc[mi][ni] = (f32x4){0.f, 0.f, 0.f, 0.f};

  for (int t = 0; t < NT; ++t){
    const int tp = (t + koff) & (NT - 1);      // physical K-tile index
    // ---- stage tile tp (linear LDS dest, pre-swizzled global source) ----
    #pragma unroll
    for (int r_ = 0; r_ < 4; ++r_){
      const unsigned short* ga_ = gA + (size_t)(r_*32 + srow) * Dsz + tp*BK + schunk*8;
      __builtin_amdgcn_global_load_lds(
        (const __attribute__((address_space(1))) unsigned int*)ga_,
        (__attribute__((address_space(3))) unsigned int*)&As[r_*2048 + wid*512], 16, 0, 0);
      const unsigned short* gb_ = gB + (size_t)(r_*32 + srow) * Dsz + tp*BK + schunk*8;
      __builtin_amdgcn_global_load_lds(
        (const __attribute__((address_space(1))) unsigned int*)gb_,
        (__attribute__((address_space(3))) unsigned int*)&Bs[r_*2048 + wid*512], 16, 0, 0);
    }
    __syncthreads();   // compiler drains vmcnt before barrier -> tile ready

    // ---- compute: plain C++ reads, compiler-scheduled waits ----
    #pragma unroll
    for (int kk = 0; kk < 2; ++kk){
      bf16x8 av[4], bv[4];
      const int chunk = ((kk*4 + lhi) ^ (l15 & 7)) * 8;
      #pragma unroll
      for (int mi = 0; mi < 4; ++mi)
        av[mi] = *(const bf16x8*)&As[(wr*64 + mi*16 + l15)*64 + chunk];
      #pragma unroll
      for (int ni = 0; ni < 4; ++ni)
        bv[ni] = *(const bf16x8*)&Bs[(wc*64 + ni*16 + l15)*64 + chunk];
      #pragma unroll
      for (int mi = 0; mi < 4; ++mi)
        #pragma unroll
        for (int ni = 0; ni < 4; ++ni)
          acc[mi][ni] = __builtin_amdgcn_mfma_f32_16x16x32_bf16(av[mi], bv[ni], acc[mi][ni], 0, 0, 0);
    }
    __syncthreads();   // protect LDS before next stage overwrites
  }

  // ---- fused epilogue: d2 -> dist -> exp -> *W, column-sum, atomic out ----
  const int rowbase0 = bm * BM + wr * 64;
  f32x4 rs[4];
  #pragma unroll
  for (int mi = 0; mi < 4; ++mi) rs[mi] = (f32x4){0.f, 0.f, 0.f, 0.f};

  f32x4 x2r[4];
  #pragma unroll
  for (int mi = 0; mi < 4; ++mi)
    x2r[mi] = *(const f32x4*)&x2[rowbase0 + mi * 16 + lhi * 4];

  #pragma unroll
  for (int ni = 0; ni < 4; ++ni){
    const int col = bn * BN + wc * 64 + ni * 16 + l15;
    const float c2v = c2[col], bt = beta[col], wv = W[col];
    #pragma unroll
    for (int mi = 0; mi < 4; ++mi)
      #pragma unroll
      for (int j = 0; j < 4; ++j){
        float s    = acc[mi][ni][j];
        float d2   = x2r[mi][j] + c2v - 2.0f * s;
        float dist = sqrtf(fmaxf(d2, 0.0f));
        rs[mi][j] += wv * __expf(-bt * dist);   // exp(<=0) can't be inf
      }
  }

  // reduce over the 16 lanes holding different cols; one atomicAdd per row
  #pragma unroll
  for (int mi = 0; mi < 4; ++mi){
    #pragma unroll
    for (int j = 0; j < 4; ++j){
      float v = rs[mi][j];
      v += __shfl_xor(v, 1, 16);
      v += __shfl_xor(v, 2, 16);
      v += __shfl_xor(v, 4, 16);
      v += __shfl_xor(v, 8, 16);
      if (l15 == 0)
        atomicAdd(&out[rowbase0 + mi * 16 + lhi * 4 + j], v);
    }
  }
}

// ---------------- naive f32 fallback (only if ws too small) ----------------
__global__ __launch_bounds__(256) void rbf_naive_kernel(
    const float* __restrict__ x, const float* __restrict__ cen,
    const float* __restrict__ beta, const float* __restrict__ W,
    const float* __restrict__ bias, float* __restrict__ out)
{
  __shared__ float4 xs4[Dsz / 4];
  __shared__ float red[256];
  int b = blockIdx.x;
  for (int i = threadIdx.x; i < Dsz / 4; i += 256)
    xs4[i] = ((const float4*)(x + (size_t)b * Dsz))[i];
  __syncthreads();
  float acc = 0.f;
  for (int j = threadIdx.x; j < Csz; j += 256){
    const float4* c4 = (const float4*)(cen + (size_t)j * Dsz);
    float d2 = 0.f;
    for (int k = 0; k < Dsz / 4; ++k){
      float4 cv = c4[k], xv = xs4[k];
      float a0 = xv.x - cv.x, a1 = xv.y - cv.y, a2 = xv.z - cv.z, a3 = xv.w - cv.w;
      d2 += a0*a0 + a1*a1 + a2*a2 + a3*a3;
    }
    acc += W[j] * expf(-beta[j] * sqrtf(fmaxf(d2, 0.f)));
  }
  red[threadIdx.x] = acc;
  __syncthreads();
  for (int s = 128; s >= 1; s >>= 1){
    if (threadIdx.x < s) red[threadIdx.x] += red[threadIdx.x + s];
    __syncthreads();
  }
  if (threadIdx.x == 0) out[b] = red[0] + bias[0];
}

extern "C" void kernel_launch(void* const* d_in, const int* in_sizes, int n_in,
                              void* d_out, int out_size, void* d_ws, size_t ws_size,
                              hipStream_t stream)
{
  const float* x    = (const float*)d_in[0];
  const float* cen  = (const float*)d_in[1];
  const float* beta = (const float*)d_in[2];
  const float* W    = (const float*)d_in[3];
  const float* bias = (const float*)d_in[4];
  float* out = (float*)d_out;

  const size_t off_xb = 0;
  const size_t off_cb = off_xb + (size_t)Bsz * Dsz * sizeof(unsigned short);
  const size_t off_x2 = off_cb + (size_t)Csz * Dsz * sizeof(unsigned short);
  const size_t off_c2 = off_x2 + (size_t)Bsz * sizeof(float);
  const size_t need   = off_c2 + (size_t)Csz * sizeof(float);

  if (ws_size < need){
    rbf_naive_kernel<<<Bsz, 256, 0, stream>>>(x, cen, beta, W, bias, out);
    return;
  }

  char* ws = (char*)d_ws;
  unsigned short* xb = (unsigned short*)(ws + off_xb);
  unsigned short* cb = (unsigned short*)(ws + off_cb);
  float* x2 = (float*)(ws + off_x2);
  float* c2 = (float*)(ws + off_c2);

  prep_kernel<<<1024, 256, 0, stream>>>(x, cen, bias, xb, cb, x2, c2, out);
  rbf_gemm_kernel<<<1024, 256, 0, stream>>>(xb, cb, x2, c2, beta, W, out);
}